// Round 11
// baseline (377.397 us; speedup 1.0000x reference)
//
#include <hip/hip_runtime.h>
#include <hip/hip_bf16.h>

#define H 64
#define SCAN_CHUNK 512
#define NB1 512          // edge partition blocks (hist = 256*NB1 per direction)
#define NBL 256          // label partition blocks (hist = 256*NBL)
#define MROWS 128        // rows per fused gather+mm block
#define MSTRIDE 72       // u16 LDS row stride (144 B: 16B-aligned, 2-way banks)

typedef unsigned short u16;
typedef unsigned int u32;
typedef unsigned char u8;
typedef __attribute__((ext_vector_type(8))) __bf16 bf16x8;
typedef __attribute__((ext_vector_type(4))) float f32x4;
typedef __attribute__((ext_vector_type(2))) float f32x2;

__device__ __forceinline__ float bflo(u32 u) {
    return __builtin_bit_cast(float, u << 16);
}
__device__ __forceinline__ float bfhi(u32 u) {
    return __builtin_bit_cast(float, u & 0xffff0000u);
}
__device__ __forceinline__ u16 bf16rne(float f) {
    u32 u = __builtin_bit_cast(u32, f);
    return (u16)((u + 0x7FFFu + ((u >> 16) & 1u)) >> 16);
}

// ---------------------------------------------------------------------------
// Fused: [0,NB1) edge histogram; [NB1,NB1+NBL) label histogram (by gene
// bucket); rest: table conversion gene->bf16+fp8(x16), dis->bf16.
// ---------------------------------------------------------------------------
__global__ __launch_bounds__(256) void fused_count_convert_kernel(
    const int* __restrict__ es, const int* __restrict__ ed,
    int* __restrict__ histD, int* __restrict__ histG,
    int ne, int shiftD, int shiftG,
    const int* __restrict__ ls, int* __restrict__ histL, int nl,
    const float* __restrict__ a, u16* __restrict__ oa, u32* __restrict__ oa8,
    long long na4,
    const float* __restrict__ b, u16* __restrict__ ob, long long nb4)
{
    if (blockIdx.x < NB1) {
        __shared__ int lhd[256], lhg[256];
        const int tid = threadIdx.x;
        lhd[tid] = 0; lhg[tid] = 0;
        __syncthreads();
        const int chunk = (ne + NB1 - 1) / NB1;
        const int e0 = blockIdx.x * chunk;
        const int e1 = min(e0 + chunk, ne);
        for (int e = e0 + tid; e < e1; e += 256) {
            atomicAdd(&lhd[ed[e] >> shiftD], 1);
            atomicAdd(&lhg[es[e] >> shiftG], 1);
        }
        __syncthreads();
        histD[tid * NB1 + blockIdx.x] = lhd[tid];
        histG[tid * NB1 + blockIdx.x] = lhg[tid];
        return;
    }
    if (blockIdx.x < NB1 + NBL) {
        __shared__ int lhl[256];
        const int tid = threadIdx.x;
        const int blk = blockIdx.x - NB1;
        lhl[tid] = 0;
        __syncthreads();
        const int chunk = (nl + NBL - 1) / NBL;
        const int e0 = blk * chunk;
        const int e1 = min(e0 + chunk, nl);
        for (int e = e0 + tid; e < e1; e += 256)
            atomicAdd(&lhl[ls[e] >> shiftG], 1);
        __syncthreads();
        histL[tid * NBL + blk] = lhl[tid];
        return;
    }
    long long i = (long long)(blockIdx.x - NB1 - NBL) * 256 + threadIdx.x;
    if (i < na4) {
        float4 v = *(const float4*)&a[i * 4];
        ushort4 o;
        o.x = bf16rne(v.x); o.y = bf16rne(v.y);
        o.z = bf16rne(v.z); o.w = bf16rne(v.w);
        *(ushort4*)&oa[i * 4] = o;
        int r = 0;
        r = __builtin_amdgcn_cvt_pk_fp8_f32(v.x * 16.0f, v.y * 16.0f, r, false);
        r = __builtin_amdgcn_cvt_pk_fp8_f32(v.z * 16.0f, v.w * 16.0f, r, true);
        oa8[i] = (u32)r;
    } else if (i < na4 + nb4) {
        long long q = i - na4;
        float4 v = *(const float4*)&b[q * 4];
        ushort4 o;
        o.x = bf16rne(v.x); o.y = bf16rne(v.y);
        o.z = bf16rne(v.z); o.w = bf16rne(v.w);
        *(ushort4*)&ob[q * 4] = o;
    }
}

// ---------------------------------------------------------------------------
// Scan phase A: per-block reduce (3 segments: histD, histG, histL).
// ---------------------------------------------------------------------------
__global__ __launch_bounds__(256) void scan_reduce_kernel(
    const int* __restrict__ a1, int n1_, const int* __restrict__ a2, int n2_,
    const int* __restrict__ a3, int n3_, int B1, int B2,
    int* __restrict__ partial)
{
    const int b = blockIdx.x;
    const int* a; int n, base;
    if (b < B1)          { a = a1; n = n1_; base = b * SCAN_CHUNK; }
    else if (b < B1 + B2){ a = a2; n = n2_; base = (b - B1) * SCAN_CHUNK; }
    else                 { a = a3; n = n3_; base = (b - B1 - B2) * SCAN_CHUNK; }
    int t = threadIdx.x;
    int i0 = base + 2 * t, i1 = i0 + 1;
    int v = ((i0 < n) ? a[i0] : 0) + ((i1 < n) ? a[i1] : 0);
    #pragma unroll
    for (int off = 32; off > 0; off >>= 1) v += __shfl_down(v, off, 64);
    __shared__ int ws[4];
    if ((t & 63) == 0) ws[t >> 6] = v;
    __syncthreads();
    if (t == 0) partial[b] = ws[0] + ws[1] + ws[2] + ws[3];
}

// ---------------------------------------------------------------------------
// Scan phase B+C merged (3 segments): every block scans all partials in LDS
// for its offset, then scans its chunk. Block 0 writes segment totals.
// ---------------------------------------------------------------------------
__global__ __launch_bounds__(256) void scan_apply_kernel(
    const int* __restrict__ a1, int* __restrict__ out1, int n1_,
    const int* __restrict__ a2, int* __restrict__ out2, int n2_,
    const int* __restrict__ a3, int* __restrict__ out3, int n3_,
    int B1, int B2, int nbtot, const int* __restrict__ partial)
{
    __shared__ int sExcl[1024];
    __shared__ int ws[4];
    const int tid = threadIdx.x;
    const int lane = tid & 63, wid = tid >> 6;

    int j0 = 4 * tid;
    int p0 = (j0 + 0 < nbtot) ? partial[j0 + 0] : 0;
    int p1 = (j0 + 1 < nbtot) ? partial[j0 + 1] : 0;
    int p2 = (j0 + 2 < nbtot) ? partial[j0 + 2] : 0;
    int p3 = (j0 + 3 < nbtot) ? partial[j0 + 3] : 0;
    int psum = p0 + p1 + p2 + p3;
    int P = psum;
    #pragma unroll
    for (int off = 1; off < 64; off <<= 1) {
        int u = __shfl_up(P, off, 64);
        if (lane >= off) P += u;
    }
    if (lane == 63) ws[wid] = P;
    __syncthreads();
    int wbase = 0;
    #pragma unroll
    for (int w = 0; w < 4; ++w) wbase += (w < wid) ? ws[w] : 0;
    int e = wbase + (P - psum);
    sExcl[j0 + 0] = e;
    sExcl[j0 + 1] = e + p0;
    sExcl[j0 + 2] = e + p0 + p1;
    sExcl[j0 + 3] = e + p0 + p1 + p2;
    __syncthreads();

    const int b = blockIdx.x;
    int tot1 = sExcl[B1 - 1] + partial[B1 - 1];
    int totA = sExcl[B1 + B2 - 1] + partial[B1 + B2 - 1];
    int tot2 = totA - tot1;
    int myOff = sExcl[b] - ((b >= B1) ? tot1 : 0) - ((b >= B1 + B2) ? tot2 : 0);
    if (b == 0 && tid == 0) {
        int tot3 = sExcl[nbtot - 1] + partial[nbtot - 1] - totA;
        out1[n1_] = tot1;
        out2[n2_] = tot2;
        out3[n3_] = tot3;
    }
    __syncthreads();

    const int* a; int* out; int n, base;
    if (b < B1)          { a = a1; out = out1; n = n1_; base = b * SCAN_CHUNK; }
    else if (b < B1 + B2){ a = a2; out = out2; n = n2_; base = (b - B1) * SCAN_CHUNK; }
    else                 { a = a3; out = out3; n = n3_; base = (b - B1 - B2) * SCAN_CHUNK; }
    int i0 = base + 2 * tid, i1 = i0 + 1;
    int x0 = (i0 < n) ? a[i0] : 0;
    int x1 = (i1 < n) ? a[i1] : 0;
    int p = x0 + x1;
    int Q = p;
    #pragma unroll
    for (int off = 1; off < 64; off <<= 1) {
        int u = __shfl_up(Q, off, 64);
        if (lane >= off) Q += u;
    }
    if (lane == 63) ws[wid] = Q;
    __syncthreads();
    int waveBase = 0;
    #pragma unroll
    for (int w = 0; w < 4; ++w) waveBase += (w < wid) ? ws[w] : 0;
    int off0 = myOff + waveBase + (Q - p);
    if (i0 < n) out[i0] = off0;
    if (i1 < n) out[i1] = off0 + x0;
}

// ---------------------------------------------------------------------------
// Partition pass 2: [0,NB1) edge pairs (packed localkey<<17|other);
// [NB1,NB1+NBL) label permutation by gene bucket. LDS cursors only.
// ---------------------------------------------------------------------------
__global__ __launch_bounds__(256) void part_scatter_kernel(
    const int* __restrict__ es, const int* __restrict__ ed,
    const int* __restrict__ baseD, const int* __restrict__ baseG,
    u32* __restrict__ pairD, u32* __restrict__ pairG,
    int ne, int shiftD, int shiftG,
    const int* __restrict__ ls, const int* __restrict__ baseL,
    int* __restrict__ permL, int nl)
{
    __shared__ int curA[256], curB[256];
    const int tid = threadIdx.x;
    if (blockIdx.x < NB1) {
        curA[tid] = baseD[tid * NB1 + blockIdx.x];
        curB[tid] = baseG[tid * NB1 + blockIdx.x];
        __syncthreads();
        const int maskD = (1 << shiftD) - 1;
        const int maskG = (1 << shiftG) - 1;
        const int chunk = (ne + NB1 - 1) / NB1;
        const int e0 = blockIdx.x * chunk;
        const int e1 = min(e0 + chunk, ne);
        for (int e = e0 + tid; e < e1; e += 256) {
            int s = es[e], d = ed[e];
            int pD = atomicAdd(&curA[d >> shiftD], 1);
            pairD[pD] = ((u32)(d & maskD) << 17) | (u32)s;
            int pG = atomicAdd(&curB[s >> shiftG], 1);
            pairG[pG] = ((u32)(s & maskG) << 17) | (u32)d;
        }
    } else {
        const int blk = blockIdx.x - NB1;
        curA[tid] = baseL[tid * NBL + blk];
        __syncthreads();
        const int chunk = (nl + NBL - 1) / NBL;
        const int e0 = blk * chunk;
        const int e1 = min(e0 + chunk, nl);
        for (int e = e0 + tid; e < e1; e += 256) {
            int pos = atomicAdd(&curA[ls[e] >> shiftG], 1);
            permL[pos] = e;
        }
    }
}

// ---------------------------------------------------------------------------
// CSR finalize: one block per bucket. LDS hist -> LDS scan -> row[]; second
// sweep ranks with LDS atomics, writes idx[]. No global atomics.
// ---------------------------------------------------------------------------
__global__ __launch_bounds__(256) void csr_build_kernel(
    const u32* __restrict__ pairD, const int* __restrict__ baseD,
    int* __restrict__ rowD, int* __restrict__ idxD, int nd, int shiftD, int nbktD,
    const u32* __restrict__ pairG, const int* __restrict__ baseG,
    int* __restrict__ rowG, int* __restrict__ idxG, int ng, int shiftG, int nbktG)
{
    __shared__ int lcnt[512], lcur[512];
    __shared__ int ws[4];
    const int j = blockIdx.x & 255;
    const int isG = blockIdx.x >> 8;
    const u32* pair; const int* base; int* row; int* idx; int n, shift, nbkt;
    if (isG) { pair = pairG; base = baseG; row = rowG; idx = idxG; n = ng; shift = shiftG; nbkt = nbktG; }
    else     { pair = pairD; base = baseD; row = rowD; idx = idxD; n = nd; shift = shiftD; nbkt = nbktD; }
    if (j >= nbkt) return;

    const int tid = threadIdx.x;
    const int nLo = j << shift;
    const int nHi = min(nLo + (1 << shift), n);
    const int range = nHi - nLo;               // <= 512
    const int segBase = base[j * NB1];
    const int segEnd  = base[(j + 1) * NB1];

    lcnt[tid] = 0; lcnt[tid + 256] = 0;
    __syncthreads();
    for (int t = segBase + tid; t < segEnd; t += 256)
        atomicAdd(&lcnt[pair[t] >> 17], 1);
    __syncthreads();

    int i0 = 2 * tid, i1 = i0 + 1;
    int c0 = (i0 < range) ? lcnt[i0] : 0;
    int c1 = (i1 < range) ? lcnt[i1] : 0;
    int p = c0 + c1;
    int P = p;
    const int lane = tid & 63, wid = tid >> 6;
    #pragma unroll
    for (int off = 1; off < 64; off <<= 1) {
        int u = __shfl_up(P, off, 64);
        if (lane >= off) P += u;
    }
    if (lane == 63) ws[wid] = P;
    __syncthreads();
    int waveBase = 0;
    #pragma unroll
    for (int w = 0; w < 4; ++w) waveBase += (w < wid) ? ws[w] : 0;
    int o0 = segBase + waveBase + (P - p);
    int o1 = o0 + c0;
    if (i0 < range) { row[nLo + i0] = o0; lcur[i0] = o0; }
    if (i1 < range) { row[nLo + i1] = o1; lcur[i1] = o1; }
    if (nHi == n && tid == 0) row[n] = segEnd;
    __syncthreads();

    for (int t = segBase + tid; t < segEnd; t += 256) {
        u32 pr = pair[t];
        int pos = atomicAdd(&lcur[pr >> 17], 1);
        idx[pos] = (int)(pr & 0x1FFFFu);
    }
}

// ---------------------------------------------------------------------------
// FUSED gather-mean + SAGE-MFMA. 512 threads own MROWS=128 rows of one
// direction (block-role split D then G).
// Phase 0: stage [wl; wr] into B-frag LDS (bf16).
// Phase 1: 16 half-waves x 8 nodes gather-mean (R7 structure: 8-edge loop,
//          low VGPR). Means written as bf16 to LDS (stride 144 B).
// Phase 2: 8 waves x one 16-row tile: 16x mfma_f32_16x16x32_bf16,
//          A=mean(LDS)+x(global), B from LDS per-MFMA (keeps VGPR small),
//          bias in acc init, bf16 store.
// F8D: D gather source is fp8(x16) 64 B rows (descale folded into inv).
// ---------------------------------------------------------------------------
template <bool RELU, bool F8D>
__global__ __launch_bounds__(512, 8) void fused_gather_mm_kernel(
    const void* __restrict__ gsrcD, const u16* __restrict__ gsrcG,
    const int* __restrict__ rowD, const int* __restrict__ idxD,
    const int* __restrict__ rowG, const int* __restrict__ idxG,
    const u16* __restrict__ xD, const u16* __restrict__ xG,
    u16* __restrict__ outD, u16* __restrict__ outG,
    const float* __restrict__ wlD, const float* __restrict__ wrD,
    const float* __restrict__ bD,
    const float* __restrict__ wlG, const float* __restrict__ wrG,
    const float* __restrict__ bG,
    int nd, int ng, int MBD)
{
    __shared__ u16 sB[16 * 64 * 8];          // 16 KB weight B-frags
    __shared__ u16 sM[MROWS * MSTRIDE];      // 18 KB bf16 means

    int b = blockIdx.x;
    const void* gsrc; const int* row; const int* idx; const u16* x; u16* out;
    const float *wl, *wr, *bias; int n; bool isD;
    if (b < MBD) {
        isD = true;  gsrc = gsrcD; row = rowD; idx = idxD; x = xD; out = outD;
        wl = wlD; wr = wrD; bias = bD; n = nd;
    } else {
        b -= MBD;
        isD = false; gsrc = (const void*)gsrcG; row = rowG; idx = idxG; x = xG;
        out = outG; wl = wlG; wr = wrG; bias = bG; n = ng;
    }
    const int row0 = b * MROWS;
    const int tid = threadIdx.x;

    // Phase 0: weights -> B-frag layout
    for (int i = tid; i < 4096; i += 512) {
        int k = i >> 6, ncol = i & 63;
        int q = (k >> 3) & 3, j = k & 7, t = ncol >> 4, n15 = ncol & 15;
        int lane = q * 16 + n15;
        int c0 = k >> 5;
        sB[(((c0 + 0) * 4 + t) * 64 + lane) * 8 + j] = bf16rne(wl[i]);
        sB[(((c0 + 2) * 4 + t) * 64 + lane) * 8 + j] = bf16rne(wr[i]);
    }

    // Phase 1: gather-mean into sM
    {
        const int hw = tid >> 5;
        const int l5 = tid & 31;
        const int sub = l5 >> 3;
        const int c8 = l5 & 7;
        for (int t = 0; t < 8; ++t) {
            int lr = hw * 8 + t;
            int node = row0 + lr;
            if (node >= n) break;
            int beg = row[node], end = row[node + 1];
            float a0[8], a1[8];
            #pragma unroll
            for (int j = 0; j < 8; ++j) { a0[j] = 0.f; a1[j] = 0.f; }

            if (F8D && isD) {
                const u8* src8 = (const u8*)gsrc;
                int i = beg;
                for (; i + 8 <= end; i += 8) {
                    int s0 = idx[i + sub];
                    int s1 = idx[i + 4 + sub];
                    uint2 v0 = *((const uint2*)(src8 + (size_t)s0 * 64) + c8);
                    uint2 v1 = *((const uint2*)(src8 + (size_t)s1 * 64) + c8);
                    f32x2 f;
                    f = __builtin_amdgcn_cvt_pk_f32_fp8((int)v0.x, false); a0[0] += f.x; a0[1] += f.y;
                    f = __builtin_amdgcn_cvt_pk_f32_fp8((int)v0.x, true);  a0[2] += f.x; a0[3] += f.y;
                    f = __builtin_amdgcn_cvt_pk_f32_fp8((int)v0.y, false); a0[4] += f.x; a0[5] += f.y;
                    f = __builtin_amdgcn_cvt_pk_f32_fp8((int)v0.y, true);  a0[6] += f.x; a0[7] += f.y;
                    f = __builtin_amdgcn_cvt_pk_f32_fp8((int)v1.x, false); a1[0] += f.x; a1[1] += f.y;
                    f = __builtin_amdgcn_cvt_pk_f32_fp8((int)v1.x, true);  a1[2] += f.x; a1[3] += f.y;
                    f = __builtin_amdgcn_cvt_pk_f32_fp8((int)v1.y, false); a1[4] += f.x; a1[5] += f.y;
                    f = __builtin_amdgcn_cvt_pk_f32_fp8((int)v1.y, true);  a1[6] += f.x; a1[7] += f.y;
                }
                if (i + 4 <= end) {
                    int s0 = idx[i + sub];
                    uint2 v0 = *((const uint2*)(src8 + (size_t)s0 * 64) + c8);
                    f32x2 f;
                    f = __builtin_amdgcn_cvt_pk_f32_fp8((int)v0.x, false); a0[0] += f.x; a0[1] += f.y;
                    f = __builtin_amdgcn_cvt_pk_f32_fp8((int)v0.x, true);  a0[2] += f.x; a0[3] += f.y;
                    f = __builtin_amdgcn_cvt_pk_f32_fp8((int)v0.y, false); a0[4] += f.x; a0[5] += f.y;
                    f = __builtin_amdgcn_cvt_pk_f32_fp8((int)v0.y, true);  a0[6] += f.x; a0[7] += f.y;
                    i += 4;
                }
                if (i + sub < end) {
                    int s1 = idx[i + sub];
                    uint2 v1 = *((const uint2*)(src8 + (size_t)s1 * 64) + c8);
                    f32x2 f;
                    f = __builtin_amdgcn_cvt_pk_f32_fp8((int)v1.x, false); a1[0] += f.x; a1[1] += f.y;
                    f = __builtin_amdgcn_cvt_pk_f32_fp8((int)v1.x, true);  a1[2] += f.x; a1[3] += f.y;
                    f = __builtin_amdgcn_cvt_pk_f32_fp8((int)v1.y, false); a1[4] += f.x; a1[5] += f.y;
                    f = __builtin_amdgcn_cvt_pk_f32_fp8((int)v1.y, true);  a1[6] += f.x; a1[7] += f.y;
                }
            } else {
                const u16* src = (const u16*)gsrc;
                int i = beg;
                for (; i + 8 <= end; i += 8) {
                    int s0 = idx[i + sub];
                    int s1 = idx[i + 4 + sub];
                    uint4 v0 = *((const uint4*)(src + (size_t)s0 * H) + c8);
                    uint4 v1 = *((const uint4*)(src + (size_t)s1 * H) + c8);
                    a0[0] += bflo(v0.x); a0[1] += bfhi(v0.x); a0[2] += bflo(v0.y); a0[3] += bfhi(v0.y);
                    a0[4] += bflo(v0.z); a0[5] += bfhi(v0.z); a0[6] += bflo(v0.w); a0[7] += bfhi(v0.w);
                    a1[0] += bflo(v1.x); a1[1] += bfhi(v1.x); a1[2] += bflo(v1.y); a1[3] += bfhi(v1.y);
                    a1[4] += bflo(v1.z); a1[5] += bfhi(v1.z); a1[6] += bflo(v1.w); a1[7] += bfhi(v1.w);
                }
                if (i + 4 <= end) {
                    int s0 = idx[i + sub];
                    uint4 v0 = *((const uint4*)(src + (size_t)s0 * H) + c8);
                    a0[0] += bflo(v0.x); a0[1] += bfhi(v0.x); a0[2] += bflo(v0.y); a0[3] += bfhi(v0.y);
                    a0[4] += bflo(v0.z); a0[5] += bfhi(v0.z); a0[6] += bflo(v0.w); a0[7] += bfhi(v0.w);
                    i += 4;
                }
                if (i + sub < end) {
                    int s1 = idx[i + sub];
                    uint4 v1 = *((const uint4*)(src + (size_t)s1 * H) + c8);
                    a1[0] += bflo(v1.x); a1[1] += bfhi(v1.x); a1[2] += bflo(v1.y); a1[3] += bfhi(v1.y);
                    a1[4] += bflo(v1.z); a1[5] += bfhi(v1.z); a1[6] += bflo(v1.w); a1[7] += bfhi(v1.w);
                }
            }

            float acc[8];
            #pragma unroll
            for (int j = 0; j < 8; ++j) acc[j] = a0[j] + a1[j];
            #pragma unroll
            for (int j = 0; j < 8; ++j) {
                acc[j] += __shfl_xor(acc[j], 8, 64);
                acc[j] += __shfl_xor(acc[j], 16, 64);
            }
            if (sub == 0) {
                float inv = 1.0f / fmaxf((float)(end - beg), 1.0f);
                if (F8D && isD) inv *= 0.0625f;
                u32 w0 = (u32)bf16rne(acc[0] * inv) | ((u32)bf16rne(acc[1] * inv) << 16);
                u32 w1 = (u32)bf16rne(acc[2] * inv) | ((u32)bf16rne(acc[3] * inv) << 16);
                u32 w2 = (u32)bf16rne(acc[4] * inv) | ((u32)bf16rne(acc[5] * inv) << 16);
                u32 w3 = (u32)bf16rne(acc[6] * inv) | ((u32)bf16rne(acc[7] * inv) << 16);
                *(uint4*)(sM + lr * MSTRIDE + c8 * 8) = make_uint4(w0, w1, w2, w3);
            }
        }
    }
    __syncthreads();

    // Phase 2: MFMA — wave w handles rows [row0+w*16, +16)
    const int lane = tid & 63;
    const int wave = tid >> 6;
    const int m = lane & 15;
    const int q = lane >> 4;
    int rbase = row0 + wave * 16;
    if (rbase >= n) return;

    const u16* mrowp = sM + (wave * 16 + m) * MSTRIDE;
    bf16x8 A0 = __builtin_bit_cast(bf16x8, *(const uint4*)(mrowp + q * 8));
    bf16x8 A1 = __builtin_bit_cast(bf16x8, *(const uint4*)(mrowp + q * 8 + 32));
    int gr = min(rbase + m, n - 1);
    const uint4* xrow = (const uint4*)(x + (size_t)gr * H);
    bf16x8 A2 = __builtin_bit_cast(bf16x8, xrow[q]);
    bf16x8 A3 = __builtin_bit_cast(bf16x8, xrow[q + 4]);

    f32x4 acc[4];
    #pragma unroll
    for (int t = 0; t < 4; ++t) {
        float bv = bias[t * 16 + m];
        acc[t] = (f32x4){bv, bv, bv, bv};
    }
    const uint4* sB4 = (const uint4*)sB;
    #pragma unroll
    for (int t = 0; t < 4; ++t) {
        bf16x8 B0 = __builtin_bit_cast(bf16x8, sB4[(0 * 4 + t) * 64 + lane]);
        acc[t] = __builtin_amdgcn_mfma_f32_16x16x32_bf16(A0, B0, acc[t], 0, 0, 0);
        bf16x8 B1 = __builtin_bit_cast(bf16x8, sB4[(1 * 4 + t) * 64 + lane]);
        acc[t] = __builtin_amdgcn_mfma_f32_16x16x32_bf16(A1, B1, acc[t], 0, 0, 0);
        bf16x8 B2 = __builtin_bit_cast(bf16x8, sB4[(2 * 4 + t) * 64 + lane]);
        acc[t] = __builtin_amdgcn_mfma_f32_16x16x32_bf16(A2, B2, acc[t], 0, 0, 0);
        bf16x8 B3 = __builtin_bit_cast(bf16x8, sB4[(3 * 4 + t) * 64 + lane]);
        acc[t] = __builtin_amdgcn_mfma_f32_16x16x32_bf16(A3, B3, acc[t], 0, 0, 0);
    }
    #pragma unroll
    for (int reg = 0; reg < 4; ++reg) {
        int orow = rbase + q * 4 + reg;
        if (orow < n) {
            u16* op = out + (size_t)orow * H;
            #pragma unroll
            for (int t = 0; t < 4; ++t) {
                float v = acc[t][reg];
                if (RELU) v = fmaxf(v, 0.0f);
                op[t * 16 + m] = bf16rne(v);
            }
        }
    }
}

// ---------------------------------------------------------------------------
// Classifier, gene-bucket-sorted order via permL: consecutive work items
// share gene buckets -> h2G reads cluster in 64 KB windows (L2 hits).
// 8 lanes per edge, uint4 loads, fp32 dot, 3-stage xor reduce.
// ---------------------------------------------------------------------------
__global__ __launch_bounds__(256) void classify_kernel(
    const u16* __restrict__ hg2, const u16* __restrict__ hd2,
    const int* __restrict__ ls, const int* __restrict__ ld,
    const int* __restrict__ permL,
    float* __restrict__ out, int nl)
{
    long long t = (long long)blockIdx.x * blockDim.x + threadIdx.x;
    int i = (int)(t >> 3);
    int c8 = (int)(t & 7);
    if (i >= nl) return;
    int e = permL[i];
    int a = ls[e];
    int b = ld[e];
    uint4 ua = *((const uint4*)(hg2 + (size_t)a * H) + c8);
    uint4 ub = *((const uint4*)(hd2 + (size_t)b * H) + c8);
    float v = bflo(ua.x) * bflo(ub.x) + bfhi(ua.x) * bfhi(ub.x)
            + bflo(ua.y) * bflo(ub.y) + bfhi(ua.y) * bfhi(ub.y)
            + bflo(ua.z) * bflo(ub.z) + bfhi(ua.z) * bfhi(ub.z)
            + bflo(ua.w) * bflo(ub.w) + bfhi(ua.w) * bfhi(ub.w);
    v += __shfl_xor(v, 1, 64);
    v += __shfl_xor(v, 2, 64);
    v += __shfl_xor(v, 4, 64);
    if (c8 == 0) out[e] = v;
}

extern "C" void kernel_launch(void* const* d_in, const int* in_sizes, int n_in,
                              void* d_out, int out_size, void* d_ws, size_t ws_size,
                              hipStream_t stream)
{
    const float* gene  = (const float*)d_in[0];
    const float* dis   = (const float*)d_in[1];
    const float* w1gdl = (const float*)d_in[2];
    const float* w1gdr = (const float*)d_in[3];
    const float* w1dgl = (const float*)d_in[4];
    const float* w1dgr = (const float*)d_in[5];
    const float* w2gdl = (const float*)d_in[6];
    const float* w2gdr = (const float*)d_in[7];
    const float* w2dgl = (const float*)d_in[8];
    const float* w2dgr = (const float*)d_in[9];
    const float* b1gd  = (const float*)d_in[10];
    const float* b1dg  = (const float*)d_in[11];
    const float* b2gd  = (const float*)d_in[12];
    const float* b2dg  = (const float*)d_in[13];
    const int* es = (const int*)d_in[14];
    const int* ed = (const int*)d_in[15];
    const int* ls = (const int*)d_in[16];
    const int* ld = (const int*)d_in[17];

    const int ng = in_sizes[0] / H;   // 100000
    const int nd = in_sizes[1] / H;   // 30000
    const int ne = in_sizes[14];      // 1500000
    const int nl = in_sizes[16];      // 500000

    int shiftD = 0; while (((nd + (1 << shiftD) - 1) >> shiftD) > 256) ++shiftD;  // 7
    int shiftG = 0; while (((ng + (1 << shiftG) - 1) >> shiftG) > 256) ++shiftG;  // 9
    const int nbktD = (nd + (1 << shiftD) - 1) >> shiftD;
    const int nbktG = (ng + (1 << shiftG) - 1) >> shiftG;
    const int n1 = 256 * NB1;     // 131072
    const int n3 = 256 * NBL;     // 65536

    // --- Workspace layout ---
    int* rowD = (int*)d_ws;                         // nd+1
    int* rowG = rowD + nd + 1;                      // ng+1
    int* idxD = rowG + ng + 1;                      // ne
    int* idxG = idxD + ne;                          // ne
    int* permL = idxG + ne;                         // nl (lives until classify)
    u16* geneBf = (u16*)(permL + nl);               // ng*H
    u16* disBf  = geneBf + (size_t)ng * H;          // nd*H
    u16* h1Dbf  = disBf + (size_t)nd * H;           // nd*H
    u16* h1Gbf  = h1Dbf + (size_t)nd * H;           // ng*H
    u16* h2Dbf  = h1Gbf + (size_t)ng * H;           // nd*H
    u16* h2Gbf  = h2Dbf + (size_t)nd * H;           // ng*H
    uintptr_t pf8 = (uintptr_t)(h2Gbf + (size_t)ng * H);
    pf8 = (pf8 + 15) & ~(uintptr_t)15;
    u32* geneF8 = (u32*)pf8;                        // ng*16 (fp8 x16 rows)
    uintptr_t p = (uintptr_t)(geneF8 + (size_t)ng * 16);
    p = (p + 15) & ~(uintptr_t)15;
    // CSR-build scratch (dead after csr_build / part_scatter):
    int* histD = (int*)p;                           // n1
    int* histG = histD + n1;                        // n1
    int* histL = histG + n1;                        // n3
    int* baseD = histL + n3;                        // n1+1
    int* baseG = baseD + n1 + 1;                    // n1+1
    int* baseL = baseG + n1 + 1;                    // n3+1
    int* partial = baseL + n3 + 1;                  // 1024
    uintptr_t pp = (uintptr_t)(partial + 1024);
    pp = (pp + 15) & ~(uintptr_t)15;
    u32* pairD = (u32*)pp;                          // ne
    u32* pairG = pairD + ne;                        // ne

    // --- Dispatch 1: histograms (edges + labels) || table conversion ---
    const long long na4 = (long long)ng * H / 4;
    const long long nb4 = (long long)nd * H / 4;
    const int convBlocks = (int)((na4 + nb4 + 255) / 256);
    fused_count_convert_kernel<<<NB1 + NBL + convBlocks, 256, 0, stream>>>(
        es, ed, histD, histG, ne, shiftD, shiftG,
        ls, histL, nl,
        gene, geneBf, geneF8, na4, dis, disBf, nb4);

    // --- Dispatch 2-3: scans (3 segments) ---
    const int B1 = n1 / SCAN_CHUNK;          // 256
    const int B2 = B1;                       // 256
    const int B3 = n3 / SCAN_CHUNK;          // 128
    const int nbtot = B1 + B2 + B3;          // 640
    scan_reduce_kernel<<<nbtot, 256, 0, stream>>>(histD, n1, histG, n1,
                                                  histL, n3, B1, B2, partial);
    scan_apply_kernel<<<nbtot, 256, 0, stream>>>(histD, baseD, n1,
                                                 histG, baseG, n1,
                                                 histL, baseL, n3,
                                                 B1, B2, nbtot, partial);

    // --- Dispatch 4: edge pairs + label permutation ---
    part_scatter_kernel<<<NB1 + NBL, 256, 0, stream>>>(
        es, ed, baseD, baseG, pairD, pairG, ne, shiftD, shiftG,
        ls, baseL, permL, nl);

    // --- Dispatch 5: CSR finalize ---
    csr_build_kernel<<<512, 256, 0, stream>>>(
        pairD, baseD, rowD, idxD, nd, shiftD, nbktD,
        pairG, baseG, rowG, idxG, ng, shiftG, nbktG);

    const int MBD = (nd + MROWS - 1) / MROWS;   // 235
    const int MBG = (ng + MROWS - 1) / MROWS;   // 782

    // --- Dispatch 6: layer 1 fused gather+mm (fp8 gene D-gather) ---
    fused_gather_mm_kernel<true, true><<<MBD + MBG, 512, 0, stream>>>(
        geneF8, disBf, rowD, idxD, rowG, idxG,
        disBf, geneBf, h1Dbf, h1Gbf,
        w1gdl, w1gdr, b1gd, w1dgl, w1dgr, b1dg, nd, ng, MBD);

    // --- Dispatch 7: layer 2 fused gather+mm (bf16 both) ---
    fused_gather_mm_kernel<false, false><<<MBD + MBG, 512, 0, stream>>>(
        h1Gbf, h1Dbf, rowD, idxD, rowG, idxG,
        h1Dbf, h1Gbf, h2Dbf, h2Gbf,
        w2gdl, w2gdr, b2gd, w2dgl, w2dgr, b2dg, nd, ng, MBD);

    // --- Dispatch 8: classifier (gene-bucket-sorted) ---
    {
        long long threads = (long long)nl * 8;
        int blocks = (int)((threads + 255) / 256);
        classify_kernel<<<blocks, 256, 0, stream>>>(h2Gbf, h2Dbf, ls, ld,
                                                    permL, (float*)d_out, nl);
    }
}

// Round 12
// 374.121 us; speedup vs baseline: 1.0088x; 1.0088x over previous
//
#include <hip/hip_runtime.h>
#include <hip/hip_bf16.h>

#define H 64
#define SCAN_CHUNK 512
#define NB1 512          // edge partition blocks (hist = 256*NB1 per direction)
#define NBL 256          // label partition blocks (hist = 256*NBL)

typedef unsigned short u16;
typedef unsigned int u32;
typedef unsigned char u8;
typedef __attribute__((ext_vector_type(8))) __bf16 bf16x8;
typedef __attribute__((ext_vector_type(4))) float f32x4;
typedef __attribute__((ext_vector_type(2))) float f32x2;

__device__ __forceinline__ float bflo(u32 u) {
    return __builtin_bit_cast(float, u << 16);
}
__device__ __forceinline__ float bfhi(u32 u) {
    return __builtin_bit_cast(float, u & 0xffff0000u);
}
__device__ __forceinline__ u16 bf16rne(float f) {
    u32 u = __builtin_bit_cast(u32, f);
    return (u16)((u + 0x7FFFu + ((u >> 16) & 1u)) >> 16);
}

// ---------------------------------------------------------------------------
// Fused: [0,NB1) edge histogram; [NB1,NB1+NBL) label histogram (gene bucket);
// rest: table conversion gene->bf16+fp8(x16), dis->bf16.
// ---------------------------------------------------------------------------
__global__ __launch_bounds__(256) void fused_count_convert_kernel(
    const int* __restrict__ es, const int* __restrict__ ed,
    int* __restrict__ histD, int* __restrict__ histG,
    int ne, int shiftD, int shiftG,
    const int* __restrict__ ls, int* __restrict__ histL, int nl,
    const float* __restrict__ a, u16* __restrict__ oa, u32* __restrict__ oa8,
    long long na4,
    const float* __restrict__ b, u16* __restrict__ ob, long long nb4)
{
    if (blockIdx.x < NB1) {
        __shared__ int lhd[256], lhg[256];
        const int tid = threadIdx.x;
        lhd[tid] = 0; lhg[tid] = 0;
        __syncthreads();
        const int chunk = (ne + NB1 - 1) / NB1;
        const int e0 = blockIdx.x * chunk;
        const int e1 = min(e0 + chunk, ne);
        for (int e = e0 + tid; e < e1; e += 256) {
            atomicAdd(&lhd[ed[e] >> shiftD], 1);
            atomicAdd(&lhg[es[e] >> shiftG], 1);
        }
        __syncthreads();
        histD[tid * NB1 + blockIdx.x] = lhd[tid];
        histG[tid * NB1 + blockIdx.x] = lhg[tid];
        return;
    }
    if (blockIdx.x < NB1 + NBL) {
        __shared__ int lhl[256];
        const int tid = threadIdx.x;
        const int blk = blockIdx.x - NB1;
        lhl[tid] = 0;
        __syncthreads();
        const int chunk = (nl + NBL - 1) / NBL;
        const int e0 = blk * chunk;
        const int e1 = min(e0 + chunk, nl);
        for (int e = e0 + tid; e < e1; e += 256)
            atomicAdd(&lhl[ls[e] >> shiftG], 1);
        __syncthreads();
        histL[tid * NBL + blk] = lhl[tid];
        return;
    }
    long long i = (long long)(blockIdx.x - NB1 - NBL) * 256 + threadIdx.x;
    if (i < na4) {
        float4 v = *(const float4*)&a[i * 4];
        ushort4 o;
        o.x = bf16rne(v.x); o.y = bf16rne(v.y);
        o.z = bf16rne(v.z); o.w = bf16rne(v.w);
        *(ushort4*)&oa[i * 4] = o;
        int r = 0;
        r = __builtin_amdgcn_cvt_pk_fp8_f32(v.x * 16.0f, v.y * 16.0f, r, false);
        r = __builtin_amdgcn_cvt_pk_fp8_f32(v.z * 16.0f, v.w * 16.0f, r, true);
        oa8[i] = (u32)r;
    } else if (i < na4 + nb4) {
        long long q = i - na4;
        float4 v = *(const float4*)&b[q * 4];
        ushort4 o;
        o.x = bf16rne(v.x); o.y = bf16rne(v.y);
        o.z = bf16rne(v.z); o.w = bf16rne(v.w);
        *(ushort4*)&ob[q * 4] = o;
    }
}

// ---------------------------------------------------------------------------
// Scan phase A: per-block reduce (3 segments: histD, histG, histL).
// ---------------------------------------------------------------------------
__global__ __launch_bounds__(256) void scan_reduce_kernel(
    const int* __restrict__ a1, int n1_, const int* __restrict__ a2, int n2_,
    const int* __restrict__ a3, int n3_, int B1, int B2,
    int* __restrict__ partial)
{
    const int b = blockIdx.x;
    const int* a; int n, base;
    if (b < B1)          { a = a1; n = n1_; base = b * SCAN_CHUNK; }
    else if (b < B1 + B2){ a = a2; n = n2_; base = (b - B1) * SCAN_CHUNK; }
    else                 { a = a3; n = n3_; base = (b - B1 - B2) * SCAN_CHUNK; }
    int t = threadIdx.x;
    int i0 = base + 2 * t, i1 = i0 + 1;
    int v = ((i0 < n) ? a[i0] : 0) + ((i1 < n) ? a[i1] : 0);
    #pragma unroll
    for (int off = 32; off > 0; off >>= 1) v += __shfl_down(v, off, 64);
    __shared__ int ws[4];
    if ((t & 63) == 0) ws[t >> 6] = v;
    __syncthreads();
    if (t == 0) partial[b] = ws[0] + ws[1] + ws[2] + ws[3];
}

// ---------------------------------------------------------------------------
// Scan phase B+C merged (3 segments): every block scans all partials in LDS
// for its offset, then scans its chunk. Block 0 writes segment totals.
// ---------------------------------------------------------------------------
__global__ __launch_bounds__(256) void scan_apply_kernel(
    const int* __restrict__ a1, int* __restrict__ out1, int n1_,
    const int* __restrict__ a2, int* __restrict__ out2, int n2_,
    const int* __restrict__ a3, int* __restrict__ out3, int n3_,
    int B1, int B2, int nbtot, const int* __restrict__ partial)
{
    __shared__ int sExcl[1024];
    __shared__ int ws[4];
    const int tid = threadIdx.x;
    const int lane = tid & 63, wid = tid >> 6;

    int j0 = 4 * tid;
    int p0 = (j0 + 0 < nbtot) ? partial[j0 + 0] : 0;
    int p1 = (j0 + 1 < nbtot) ? partial[j0 + 1] : 0;
    int p2 = (j0 + 2 < nbtot) ? partial[j0 + 2] : 0;
    int p3 = (j0 + 3 < nbtot) ? partial[j0 + 3] : 0;
    int psum = p0 + p1 + p2 + p3;
    int P = psum;
    #pragma unroll
    for (int off = 1; off < 64; off <<= 1) {
        int u = __shfl_up(P, off, 64);
        if (lane >= off) P += u;
    }
    if (lane == 63) ws[wid] = P;
    __syncthreads();
    int wbase = 0;
    #pragma unroll
    for (int w = 0; w < 4; ++w) wbase += (w < wid) ? ws[w] : 0;
    int e = wbase + (P - psum);
    sExcl[j0 + 0] = e;
    sExcl[j0 + 1] = e + p0;
    sExcl[j0 + 2] = e + p0 + p1;
    sExcl[j0 + 3] = e + p0 + p1 + p2;
    __syncthreads();

    const int b = blockIdx.x;
    int tot1 = sExcl[B1 - 1] + partial[B1 - 1];
    int totA = sExcl[B1 + B2 - 1] + partial[B1 + B2 - 1];
    int tot2 = totA - tot1;
    int myOff = sExcl[b] - ((b >= B1) ? tot1 : 0) - ((b >= B1 + B2) ? tot2 : 0);
    if (b == 0 && tid == 0) {
        int tot3 = sExcl[nbtot - 1] + partial[nbtot - 1] - totA;
        out1[n1_] = tot1;
        out2[n2_] = tot2;
        out3[n3_] = tot3;
    }
    __syncthreads();

    const int* a; int* out; int n, base;
    if (b < B1)          { a = a1; out = out1; n = n1_; base = b * SCAN_CHUNK; }
    else if (b < B1 + B2){ a = a2; out = out2; n = n2_; base = (b - B1) * SCAN_CHUNK; }
    else                 { a = a3; out = out3; n = n3_; base = (b - B1 - B2) * SCAN_CHUNK; }
    int i0 = base + 2 * tid, i1 = i0 + 1;
    int x0 = (i0 < n) ? a[i0] : 0;
    int x1 = (i1 < n) ? a[i1] : 0;
    int p = x0 + x1;
    int Q = p;
    #pragma unroll
    for (int off = 1; off < 64; off <<= 1) {
        int u = __shfl_up(Q, off, 64);
        if (lane >= off) Q += u;
    }
    if (lane == 63) ws[wid] = Q;
    __syncthreads();
    int waveBase = 0;
    #pragma unroll
    for (int w = 0; w < 4; ++w) waveBase += (w < wid) ? ws[w] : 0;
    int off0 = myOff + waveBase + (Q - p);
    if (i0 < n) out[i0] = off0;
    if (i1 < n) out[i1] = off0 + x0;
}

// ---------------------------------------------------------------------------
// Partition pass 2: [0,NB1) edge pairs (packed localkey<<17|other);
// [NB1,NB1+NBL) label permutation by gene bucket. LDS cursors only.
// ---------------------------------------------------------------------------
__global__ __launch_bounds__(256) void part_scatter_kernel(
    const int* __restrict__ es, const int* __restrict__ ed,
    const int* __restrict__ baseD, const int* __restrict__ baseG,
    u32* __restrict__ pairD, u32* __restrict__ pairG,
    int ne, int shiftD, int shiftG,
    const int* __restrict__ ls, const int* __restrict__ baseL,
    int* __restrict__ permL, int nl)
{
    __shared__ int curA[256], curB[256];
    const int tid = threadIdx.x;
    if (blockIdx.x < NB1) {
        curA[tid] = baseD[tid * NB1 + blockIdx.x];
        curB[tid] = baseG[tid * NB1 + blockIdx.x];
        __syncthreads();
        const int maskD = (1 << shiftD) - 1;
        const int maskG = (1 << shiftG) - 1;
        const int chunk = (ne + NB1 - 1) / NB1;
        const int e0 = blockIdx.x * chunk;
        const int e1 = min(e0 + chunk, ne);
        for (int e = e0 + tid; e < e1; e += 256) {
            int s = es[e], d = ed[e];
            int pD = atomicAdd(&curA[d >> shiftD], 1);
            pairD[pD] = ((u32)(d & maskD) << 17) | (u32)s;
            int pG = atomicAdd(&curB[s >> shiftG], 1);
            pairG[pG] = ((u32)(s & maskG) << 17) | (u32)d;
        }
    } else {
        const int blk = blockIdx.x - NB1;
        curA[tid] = baseL[tid * NBL + blk];
        __syncthreads();
        const int chunk = (nl + NBL - 1) / NBL;
        const int e0 = blk * chunk;
        const int e1 = min(e0 + chunk, nl);
        for (int e = e0 + tid; e < e1; e += 256) {
            int pos = atomicAdd(&curA[ls[e] >> shiftG], 1);
            permL[pos] = e;
        }
    }
}

// ---------------------------------------------------------------------------
// CSR finalize: one block per bucket. LDS hist -> LDS scan -> row[]; second
// sweep ranks with LDS atomics, writes idx[]. No global atomics.
// ---------------------------------------------------------------------------
__global__ __launch_bounds__(256) void csr_build_kernel(
    const u32* __restrict__ pairD, const int* __restrict__ baseD,
    int* __restrict__ rowD, int* __restrict__ idxD, int nd, int shiftD, int nbktD,
    const u32* __restrict__ pairG, const int* __restrict__ baseG,
    int* __restrict__ rowG, int* __restrict__ idxG, int ng, int shiftG, int nbktG)
{
    __shared__ int lcnt[512], lcur[512];
    __shared__ int ws[4];
    const int j = blockIdx.x & 255;
    const int isG = blockIdx.x >> 8;
    const u32* pair; const int* base; int* row; int* idx; int n, shift, nbkt;
    if (isG) { pair = pairG; base = baseG; row = rowG; idx = idxG; n = ng; shift = shiftG; nbkt = nbktG; }
    else     { pair = pairD; base = baseD; row = rowD; idx = idxD; n = nd; shift = shiftD; nbkt = nbktD; }
    if (j >= nbkt) return;

    const int tid = threadIdx.x;
    const int nLo = j << shift;
    const int nHi = min(nLo + (1 << shift), n);
    const int range = nHi - nLo;               // <= 512
    const int segBase = base[j * NB1];
    const int segEnd  = base[(j + 1) * NB1];

    lcnt[tid] = 0; lcnt[tid + 256] = 0;
    __syncthreads();
    for (int t = segBase + tid; t < segEnd; t += 256)
        atomicAdd(&lcnt[pair[t] >> 17], 1);
    __syncthreads();

    int i0 = 2 * tid, i1 = i0 + 1;
    int c0 = (i0 < range) ? lcnt[i0] : 0;
    int c1 = (i1 < range) ? lcnt[i1] : 0;
    int p = c0 + c1;
    int P = p;
    const int lane = tid & 63, wid = tid >> 6;
    #pragma unroll
    for (int off = 1; off < 64; off <<= 1) {
        int u = __shfl_up(P, off, 64);
        if (lane >= off) P += u;
    }
    if (lane == 63) ws[wid] = P;
    __syncthreads();
    int waveBase = 0;
    #pragma unroll
    for (int w = 0; w < 4; ++w) waveBase += (w < wid) ? ws[w] : 0;
    int o0 = segBase + waveBase + (P - p);
    int o1 = o0 + c0;
    if (i0 < range) { row[nLo + i0] = o0; lcur[i0] = o0; }
    if (i1 < range) { row[nLo + i1] = o1; lcur[i1] = o1; }
    if (nHi == n && tid == 0) row[n] = segEnd;
    __syncthreads();

    for (int t = segBase + tid; t < segEnd; t += 256) {
        u32 pr = pair[t];
        int pos = atomicAdd(&lcur[pr >> 17], 1);
        idx[pos] = (int)(pr & 0x1FFFFu);
    }
}

// ---------------------------------------------------------------------------
// Gather-mean -> bf16 means (R9/R7 structure: standalone, 8-edge loop, low
// VGPR, no block barrier — waves retire independently; measured 77% occ).
// F8D: D-nodes read fp8(x16) 64 B rows; G-nodes bf16 128 B rows.
// ---------------------------------------------------------------------------
template <bool F8D>
__global__ __launch_bounds__(256) void gather_mean_kernel(
    const void* __restrict__ srcD_, const u16* __restrict__ srcG,
    const int* __restrict__ rowD, const int* __restrict__ idxD,
    const int* __restrict__ rowG, const int* __restrict__ idxG,
    u16* __restrict__ outD, u16* __restrict__ outG, int nd, int ng)
{
    int hw = blockIdx.x * 8 + (threadIdx.x >> 5);   // half-wave id = node
    int l5 = threadIdx.x & 31;
    if (hw >= nd + ng) return;
    const bool isD = hw < nd;
    const int sub = l5 >> 3;        // 0..3: edge slot
    const int c8 = l5 & 7;          // 8-lane chunk index within row
    const int* row; const int* idx; u16* out; int node;
    if (isD) { row = rowD; idx = idxD; out = outD; node = hw; }
    else     { row = rowG; idx = idxG; out = outG; node = hw - nd; }
    int beg = row[node], end = row[node + 1];

    float a0[8], a1[8];
    #pragma unroll
    for (int j = 0; j < 8; ++j) { a0[j] = 0.f; a1[j] = 0.f; }

    if (F8D && isD) {
        const u8* src8 = (const u8*)srcD_;
        int i = beg;
        for (; i + 8 <= end; i += 8) {
            int s0 = idx[i + sub];
            int s1 = idx[i + 4 + sub];
            uint2 v0 = *((const uint2*)(src8 + (size_t)s0 * 64) + c8);
            uint2 v1 = *((const uint2*)(src8 + (size_t)s1 * 64) + c8);
            f32x2 f;
            f = __builtin_amdgcn_cvt_pk_f32_fp8((int)v0.x, false); a0[0] += f.x; a0[1] += f.y;
            f = __builtin_amdgcn_cvt_pk_f32_fp8((int)v0.x, true);  a0[2] += f.x; a0[3] += f.y;
            f = __builtin_amdgcn_cvt_pk_f32_fp8((int)v0.y, false); a0[4] += f.x; a0[5] += f.y;
            f = __builtin_amdgcn_cvt_pk_f32_fp8((int)v0.y, true);  a0[6] += f.x; a0[7] += f.y;
            f = __builtin_amdgcn_cvt_pk_f32_fp8((int)v1.x, false); a1[0] += f.x; a1[1] += f.y;
            f = __builtin_amdgcn_cvt_pk_f32_fp8((int)v1.x, true);  a1[2] += f.x; a1[3] += f.y;
            f = __builtin_amdgcn_cvt_pk_f32_fp8((int)v1.y, false); a1[4] += f.x; a1[5] += f.y;
            f = __builtin_amdgcn_cvt_pk_f32_fp8((int)v1.y, true);  a1[6] += f.x; a1[7] += f.y;
        }
        if (i + 4 <= end) {
            int s0 = idx[i + sub];
            uint2 v0 = *((const uint2*)(src8 + (size_t)s0 * 64) + c8);
            f32x2 f;
            f = __builtin_amdgcn_cvt_pk_f32_fp8((int)v0.x, false); a0[0] += f.x; a0[1] += f.y;
            f = __builtin_amdgcn_cvt_pk_f32_fp8((int)v0.x, true);  a0[2] += f.x; a0[3] += f.y;
            f = __builtin_amdgcn_cvt_pk_f32_fp8((int)v0.y, false); a0[4] += f.x; a0[5] += f.y;
            f = __builtin_amdgcn_cvt_pk_f32_fp8((int)v0.y, true);  a0[6] += f.x; a0[7] += f.y;
            i += 4;
        }
        if (i + sub < end) {
            int s1 = idx[i + sub];
            uint2 v1 = *((const uint2*)(src8 + (size_t)s1 * 64) + c8);
            f32x2 f;
            f = __builtin_amdgcn_cvt_pk_f32_fp8((int)v1.x, false); a1[0] += f.x; a1[1] += f.y;
            f = __builtin_amdgcn_cvt_pk_f32_fp8((int)v1.x, true);  a1[2] += f.x; a1[3] += f.y;
            f = __builtin_amdgcn_cvt_pk_f32_fp8((int)v1.y, false); a1[4] += f.x; a1[5] += f.y;
            f = __builtin_amdgcn_cvt_pk_f32_fp8((int)v1.y, true);  a1[6] += f.x; a1[7] += f.y;
        }
    } else {
        const u16* src = isD ? (const u16*)srcD_ : srcG;
        int i = beg;
        for (; i + 8 <= end; i += 8) {
            int s0 = idx[i + sub];
            int s1 = idx[i + 4 + sub];
            uint4 v0 = *((const uint4*)(src + (size_t)s0 * H) + c8);
            uint4 v1 = *((const uint4*)(src + (size_t)s1 * H) + c8);
            a0[0] += bflo(v0.x); a0[1] += bfhi(v0.x); a0[2] += bflo(v0.y); a0[3] += bfhi(v0.y);
            a0[4] += bflo(v0.z); a0[5] += bfhi(v0.z); a0[6] += bflo(v0.w); a0[7] += bfhi(v0.w);
            a1[0] += bflo(v1.x); a1[1] += bfhi(v1.x); a1[2] += bflo(v1.y); a1[3] += bfhi(v1.y);
            a1[4] += bflo(v1.z); a1[5] += bfhi(v1.z); a1[6] += bflo(v1.w); a1[7] += bfhi(v1.w);
        }
        if (i + 4 <= end) {
            int s0 = idx[i + sub];
            uint4 v0 = *((const uint4*)(src + (size_t)s0 * H) + c8);
            a0[0] += bflo(v0.x); a0[1] += bfhi(v0.x); a0[2] += bflo(v0.y); a0[3] += bfhi(v0.y);
            a0[4] += bflo(v0.z); a0[5] += bfhi(v0.z); a0[6] += bflo(v0.w); a0[7] += bfhi(v0.w);
            i += 4;
        }
        if (i + sub < end) {
            int s1 = idx[i + sub];
            uint4 v1 = *((const uint4*)(src + (size_t)s1 * H) + c8);
            a1[0] += bflo(v1.x); a1[1] += bfhi(v1.x); a1[2] += bflo(v1.y); a1[3] += bfhi(v1.y);
            a1[4] += bflo(v1.z); a1[5] += bfhi(v1.z); a1[6] += bflo(v1.w); a1[7] += bfhi(v1.w);
        }
    }

    float acc[8];
    #pragma unroll
    for (int j = 0; j < 8; ++j) acc[j] = a0[j] + a1[j];
    #pragma unroll
    for (int j = 0; j < 8; ++j) {
        acc[j] += __shfl_xor(acc[j], 8, 64);
        acc[j] += __shfl_xor(acc[j], 16, 64);
    }
    if (sub == 0) {
        float inv = 1.0f / fmaxf((float)(end - beg), 1.0f);
        if (F8D && isD) inv *= 0.0625f;   // undo x16 fp8 encode scale
        u32 w0 = (u32)bf16rne(acc[0] * inv) | ((u32)bf16rne(acc[1] * inv) << 16);
        u32 w1 = (u32)bf16rne(acc[2] * inv) | ((u32)bf16rne(acc[3] * inv) << 16);
        u32 w2 = (u32)bf16rne(acc[4] * inv) | ((u32)bf16rne(acc[5] * inv) << 16);
        u32 w3 = (u32)bf16rne(acc[6] * inv) | ((u32)bf16rne(acc[7] * inv) << 16);
        uint4 pk = make_uint4(w0, w1, w2, w3);
        *(uint4*)(out + (size_t)node * H + c8 * 8) = pk;
    }
}

// ---------------------------------------------------------------------------
// SAGE linear via MFMA, BOTH directions in one dispatch (R7/R9 version).
// ---------------------------------------------------------------------------
template <bool RELU>
__global__ __launch_bounds__(256) void sage_mm_mfma_kernel(
    const u16* __restrict__ meanD, const u16* __restrict__ xD, u16* __restrict__ outD,
    const float* __restrict__ wlD, const float* __restrict__ wrD,
    const float* __restrict__ bD, int nd,
    const u16* __restrict__ meanG, const u16* __restrict__ xG, u16* __restrict__ outG,
    const float* __restrict__ wlG, const float* __restrict__ wrG,
    const float* __restrict__ bG, int ng, int MBD)
{
    __shared__ u16 sB[16 * 64 * 8];   // [frag=c*4+t][lane][j]
    int b = blockIdx.x;
    const u16 *mean, *x; u16* out; const float *wl, *wr, *bias; int n;
    if (b < MBD) { mean = meanD; x = xD; out = outD; wl = wlD; wr = wrD; bias = bD; n = nd; }
    else { b -= MBD; mean = meanG; x = xG; out = outG; wl = wlG; wr = wrG; bias = bG; n = ng; }

    const int tid = threadIdx.x;
    for (int i = tid; i < 4096; i += 256) {
        int k = i >> 6, ncol = i & 63;
        int q = (k >> 3) & 3, j = k & 7, t = ncol >> 4, n15 = ncol & 15;
        int lane = q * 16 + n15;
        int c0 = k >> 5;                     // 0..1
        sB[(((c0 + 0) * 4 + t) * 64 + lane) * 8 + j] = bf16rne(wl[i]);
        sB[(((c0 + 2) * 4 + t) * 64 + lane) * 8 + j] = bf16rne(wr[i]);
    }
    __syncthreads();

    const int lane = tid & 63;
    const int wave = tid >> 6;
    const int m = lane & 15;
    const int q = lane >> 4;

    bf16x8 Bf[16];
    {
        const uint4* sB4 = (const uint4*)sB;
        #pragma unroll
        for (int f = 0; f < 16; ++f)
            Bf[f] = __builtin_bit_cast(bf16x8, sB4[f * 64 + lane]);
    }
    float bv[4];
    #pragma unroll
    for (int t = 0; t < 4; ++t) bv[t] = bias[t * 16 + m];

    const int row0 = b * 256;
    #pragma unroll
    for (int r = 0; r < 4; ++r) {
        int rbase = row0 + (wave + 4 * r) * 16;   // wave-uniform
        if (rbase >= n) break;
        int gr = min(rbase + m, n - 1);
        const uint4* mrow = (const uint4*)(mean + (size_t)gr * H);
        const uint4* xrow = (const uint4*)(x + (size_t)gr * H);
        bf16x8 A0 = __builtin_bit_cast(bf16x8, mrow[q]);
        bf16x8 A1 = __builtin_bit_cast(bf16x8, mrow[q + 4]);
        bf16x8 A2 = __builtin_bit_cast(bf16x8, xrow[q]);
        bf16x8 A3 = __builtin_bit_cast(bf16x8, xrow[q + 4]);
        f32x4 acc[4];
        #pragma unroll
        for (int t = 0; t < 4; ++t) acc[t] = (f32x4){bv[t], bv[t], bv[t], bv[t]};
        #pragma unroll
        for (int t = 0; t < 4; ++t) {
            acc[t] = __builtin_amdgcn_mfma_f32_16x16x32_bf16(A0, Bf[0 * 4 + t], acc[t], 0, 0, 0);
            acc[t] = __builtin_amdgcn_mfma_f32_16x16x32_bf16(A1, Bf[1 * 4 + t], acc[t], 0, 0, 0);
            acc[t] = __builtin_amdgcn_mfma_f32_16x16x32_bf16(A2, Bf[2 * 4 + t], acc[t], 0, 0, 0);
            acc[t] = __builtin_amdgcn_mfma_f32_16x16x32_bf16(A3, Bf[3 * 4 + t], acc[t], 0, 0, 0);
        }
        #pragma unroll
        for (int reg = 0; reg < 4; ++reg) {
            int orow = rbase + q * 4 + reg;
            if (orow < n) {
                u16* op = out + (size_t)orow * H;
                #pragma unroll
                for (int t = 0; t < 4; ++t) {
                    float v = acc[t][reg];
                    if (RELU) v = fmaxf(v, 0.0f);
                    op[t * 16 + m] = bf16rne(v);
                }
            }
        }
    }
}

// ---------------------------------------------------------------------------
// Classifier, gene-bucket-sorted via permL (h2G reads cluster -> L2 hits).
// 8 lanes per edge, uint4 loads, fp32 dot, 3-stage xor reduce.
// ---------------------------------------------------------------------------
__global__ __launch_bounds__(256) void classify_kernel(
    const u16* __restrict__ hg2, const u16* __restrict__ hd2,
    const int* __restrict__ ls, const int* __restrict__ ld,
    const int* __restrict__ permL,
    float* __restrict__ out, int nl)
{
    long long t = (long long)blockIdx.x * blockDim.x + threadIdx.x;
    int i = (int)(t >> 3);
    int c8 = (int)(t & 7);
    if (i >= nl) return;
    int e = permL[i];
    int a = ls[e];
    int b = ld[e];
    uint4 ua = *((const uint4*)(hg2 + (size_t)a * H) + c8);
    uint4 ub = *((const uint4*)(hd2 + (size_t)b * H) + c8);
    float v = bflo(ua.x) * bflo(ub.x) + bfhi(ua.x) * bfhi(ub.x)
            + bflo(ua.y) * bflo(ub.y) + bfhi(ua.y) * bfhi(ub.y)
            + bflo(ua.z) * bflo(ub.z) + bfhi(ua.z) * bfhi(ub.z)
            + bflo(ua.w) * bflo(ub.w) + bfhi(ua.w) * bfhi(ub.w);
    v += __shfl_xor(v, 1, 64);
    v += __shfl_xor(v, 2, 64);
    v += __shfl_xor(v, 4, 64);
    if (c8 == 0) out[e] = v;
}

extern "C" void kernel_launch(void* const* d_in, const int* in_sizes, int n_in,
                              void* d_out, int out_size, void* d_ws, size_t ws_size,
                              hipStream_t stream)
{
    const float* gene  = (const float*)d_in[0];
    const float* dis   = (const float*)d_in[1];
    const float* w1gdl = (const float*)d_in[2];
    const float* w1gdr = (const float*)d_in[3];
    const float* w1dgl = (const float*)d_in[4];
    const float* w1dgr = (const float*)d_in[5];
    const float* w2gdl = (const float*)d_in[6];
    const float* w2gdr = (const float*)d_in[7];
    const float* w2dgl = (const float*)d_in[8];
    const float* w2dgr = (const float*)d_in[9];
    const float* b1gd  = (const float*)d_in[10];
    const float* b1dg  = (const float*)d_in[11];
    const float* b2gd  = (const float*)d_in[12];
    const float* b2dg  = (const float*)d_in[13];
    const int* es = (const int*)d_in[14];
    const int* ed = (const int*)d_in[15];
    const int* ls = (const int*)d_in[16];
    const int* ld = (const int*)d_in[17];

    const int ng = in_sizes[0] / H;   // 100000
    const int nd = in_sizes[1] / H;   // 30000
    const int ne = in_sizes[14];      // 1500000
    const int nl = in_sizes[16];      // 500000

    int shiftD = 0; while (((nd + (1 << shiftD) - 1) >> shiftD) > 256) ++shiftD;  // 7
    int shiftG = 0; while (((ng + (1 << shiftG) - 1) >> shiftG) > 256) ++shiftG;  // 9
    const int nbktD = (nd + (1 << shiftD) - 1) >> shiftD;
    const int nbktG = (ng + (1 << shiftG) - 1) >> shiftG;
    const int n1 = 256 * NB1;     // 131072
    const int n3 = 256 * NBL;     // 65536

    // --- Workspace layout ---
    int* rowD = (int*)d_ws;                         // nd+1
    int* rowG = rowD + nd + 1;                      // ng+1
    int* idxD = rowG + ng + 1;                      // ne
    int* idxG = idxD + ne;                          // ne
    int* permL = idxG + ne;                         // nl (lives until classify)
    u16* geneBf = (u16*)(permL + nl);               // ng*H
    u16* disBf  = geneBf + (size_t)ng * H;          // nd*H
    u16* h1Dbf  = disBf + (size_t)nd * H;           // nd*H
    u16* h1Gbf  = h1Dbf + (size_t)nd * H;           // ng*H
    u16* h2Dbf  = h1Gbf + (size_t)ng * H;           // nd*H
    u16* h2Gbf  = h2Dbf + (size_t)nd * H;           // ng*H
    uintptr_t pf8 = (uintptr_t)(h2Gbf + (size_t)ng * H);
    pf8 = (pf8 + 15) & ~(uintptr_t)15;
    u32* geneF8 = (u32*)pf8;                        // ng*16 (fp8 x16 rows)
    uintptr_t p = (uintptr_t)(geneF8 + (size_t)ng * 16);
    p = (p + 15) & ~(uintptr_t)15;
    // Union region: CSR-build scratch (dead after csr_build) aliased w/ means.
    u16* MD = (u16*)p;                              // nd*H bf16 means
    u16* MG = MD + (size_t)nd * H;                  // ng*H
    int* histD = (int*)p;                           // n1
    int* histG = histD + n1;                        // n1
    int* histL = histG + n1;                        // n3
    int* baseD = histL + n3;                        // n1+1
    int* baseG = baseD + n1 + 1;                    // n1+1
    int* baseL = baseG + n1 + 1;                    // n3+1
    int* partial = baseL + n3 + 1;                  // 1024
    uintptr_t pp = (uintptr_t)(partial + 1024);
    pp = (pp + 15) & ~(uintptr_t)15;
    u32* pairD = (u32*)pp;                          // ne
    u32* pairG = pairD + ne;                        // ne

    // --- Dispatch 1: histograms (edges + labels) || table conversion ---
    const long long na4 = (long long)ng * H / 4;
    const long long nb4 = (long long)nd * H / 4;
    const int convBlocks = (int)((na4 + nb4 + 255) / 256);
    fused_count_convert_kernel<<<NB1 + NBL + convBlocks, 256, 0, stream>>>(
        es, ed, histD, histG, ne, shiftD, shiftG,
        ls, histL, nl,
        gene, geneBf, geneF8, na4, dis, disBf, nb4);

    // --- Dispatch 2-3: scans (3 segments) ---
    const int B1 = n1 / SCAN_CHUNK;          // 256
    const int B2 = B1;                       // 256
    const int B3 = n3 / SCAN_CHUNK;          // 128
    const int nbtot = B1 + B2 + B3;          // 640
    scan_reduce_kernel<<<nbtot, 256, 0, stream>>>(histD, n1, histG, n1,
                                                  histL, n3, B1, B2, partial);
    scan_apply_kernel<<<nbtot, 256, 0, stream>>>(histD, baseD, n1,
                                                 histG, baseG, n1,
                                                 histL, baseL, n3,
                                                 B1, B2, nbtot, partial);

    // --- Dispatch 4: edge pairs + label permutation ---
    part_scatter_kernel<<<NB1 + NBL, 256, 0, stream>>>(
        es, ed, baseD, baseG, pairD, pairG, ne, shiftD, shiftG,
        ls, baseL, permL, nl);

    // --- Dispatch 5: CSR finalize ---
    csr_build_kernel<<<512, 256, 0, stream>>>(
        pairD, baseD, rowD, idxD, nd, shiftD, nbktD,
        pairG, baseG, rowG, idxG, ng, shiftG, nbktG);

    const int gatherBlocks = (nd + ng + 7) / 8;
    const int MBD = (nd + 255) / 256;
    const int MBG = (ng + 255) / 256;

    // --- Layer 1: D-gather over fp8 gene rows, G-gather over bf16 dis rows
    gather_mean_kernel<true><<<gatherBlocks, 256, 0, stream>>>(
        geneF8, disBf, rowD, idxD, rowG, idxG, MD, MG, nd, ng);
    sage_mm_mfma_kernel<true><<<MBD + MBG, 256, 0, stream>>>(
        MD, disBf, h1Dbf, w1gdl, w1gdr, b1gd, nd,
        MG, geneBf, h1Gbf, w1dgl, w1dgr, b1dg, ng, MBD);

    // --- Layer 2: both directions bf16
    gather_mean_kernel<false><<<gatherBlocks, 256, 0, stream>>>(
        h1Gbf, h1Dbf, rowD, idxD, rowG, idxG, MD, MG, nd, ng);
    sage_mm_mfma_kernel<false><<<MBD + MBG, 256, 0, stream>>>(
        MD, h1Dbf, h2Dbf, w2gdl, w2gdr, b2gd, nd,
        MG, h1Gbf, h2Gbf, w2dgl, w2dgr, b2dg, ng, MBD);

    // --- Classifier (gene-bucket-sorted) ---
    {
        long long threads = (long long)nl * 8;
        int blocks = (int)((threads + 255) / 256);
        classify_kernel<<<blocks, 256, 0, stream>>>(h2Gbf, h2Dbf, ls, ld,
                                                    permL, (float*)d_out, nl);
    }
}

// Round 13
// 331.435 us; speedup vs baseline: 1.1387x; 1.1288x over previous
//
#include <hip/hip_runtime.h>
#include <hip/hip_bf16.h>

#define H 64
#define SCAN_CHUNK 512
#define NB1 512          // edge partition blocks (hist = 256*NB1 per direction)

typedef unsigned short u16;
typedef unsigned int u32;
typedef unsigned char u8;
typedef __attribute__((ext_vector_type(8))) __bf16 bf16x8;
typedef __attribute__((ext_vector_type(4))) float f32x4;
typedef __attribute__((ext_vector_type(2))) float f32x2;

__device__ __forceinline__ float bflo(u32 u) {
    return __builtin_bit_cast(float, u << 16);
}
__device__ __forceinline__ float bfhi(u32 u) {
    return __builtin_bit_cast(float, u & 0xffff0000u);
}
__device__ __forceinline__ u16 bf16rne(float f) {
    u32 u = __builtin_bit_cast(u32, f);
    return (u16)((u + 0x7FFFu + ((u >> 16) & 1u)) >> 16);
}
__device__ __forceinline__ u8 fp8enc(float f) {   // OCP e4m3, input pre-scaled
    return (u8)(__builtin_amdgcn_cvt_pk_fp8_f32(f, 0.0f, 0, false) & 0xFF);
}

// ---------------------------------------------------------------------------
// Fused: blocks [0,NB1) = edge histogram (LDS atomics, bucket-major out);
// rest: table conversion gene/dis -> bf16 + fp8(x16, 64 B rows).
// ---------------------------------------------------------------------------
__global__ __launch_bounds__(256) void fused_count_convert_kernel(
    const int* __restrict__ es, const int* __restrict__ ed,
    int* __restrict__ histD, int* __restrict__ histG,
    int ne, int shiftD, int shiftG,
    const float* __restrict__ a, u16* __restrict__ oa, u32* __restrict__ oa8,
    long long na4,
    const float* __restrict__ b, u16* __restrict__ ob, u32* __restrict__ ob8,
    long long nb4)
{
    if (blockIdx.x < NB1) {
        __shared__ int lhd[256], lhg[256];
        const int tid = threadIdx.x;
        lhd[tid] = 0; lhg[tid] = 0;
        __syncthreads();
        const int chunk = (ne + NB1 - 1) / NB1;
        const int e0 = blockIdx.x * chunk;
        const int e1 = min(e0 + chunk, ne);
        for (int e = e0 + tid; e < e1; e += 256) {
            atomicAdd(&lhd[ed[e] >> shiftD], 1);
            atomicAdd(&lhg[es[e] >> shiftG], 1);
        }
        __syncthreads();
        histD[tid * NB1 + blockIdx.x] = lhd[tid];
        histG[tid * NB1 + blockIdx.x] = lhg[tid];
        return;
    }
    long long i = (long long)(blockIdx.x - NB1) * 256 + threadIdx.x;
    const float* src; u16* dst; u32* dst8; long long q;
    if (i < na4) { src = a; dst = oa; dst8 = oa8; q = i; }
    else if (i < na4 + nb4) { src = b; dst = ob; dst8 = ob8; q = i - na4; }
    else return;
    float4 v = *(const float4*)&src[q * 4];
    ushort4 o;
    o.x = bf16rne(v.x); o.y = bf16rne(v.y);
    o.z = bf16rne(v.z); o.w = bf16rne(v.w);
    *(ushort4*)&dst[q * 4] = o;
    int r = 0;
    r = __builtin_amdgcn_cvt_pk_fp8_f32(v.x * 16.0f, v.y * 16.0f, r, false);
    r = __builtin_amdgcn_cvt_pk_fp8_f32(v.z * 16.0f, v.w * 16.0f, r, true);
    dst8[q] = (u32)r;
}

// ---------------------------------------------------------------------------
// Scan phase A: per-block reduce of SCAN_CHUNK elements (2 segments).
// ---------------------------------------------------------------------------
__global__ __launch_bounds__(256) void scan_reduce_kernel(
    const int* __restrict__ a1, int n1, const int* __restrict__ a2, int n2,
    int B1, int* __restrict__ partial)
{
    const int b = blockIdx.x;
    const int* a; int n, base;
    if (b < B1) { a = a1; n = n1; base = b * SCAN_CHUNK; }
    else        { a = a2; n = n2; base = (b - B1) * SCAN_CHUNK; }
    int t = threadIdx.x;
    int i0 = base + 2 * t, i1 = i0 + 1;
    int v = ((i0 < n) ? a[i0] : 0) + ((i1 < n) ? a[i1] : 0);
    #pragma unroll
    for (int off = 32; off > 0; off >>= 1) v += __shfl_down(v, off, 64);
    __shared__ int ws[4];
    if ((t & 63) == 0) ws[t >> 6] = v;
    __syncthreads();
    if (t == 0) partial[b] = ws[0] + ws[1] + ws[2] + ws[3];
}

// ---------------------------------------------------------------------------
// Scan phase B+C merged: every block redundantly scans ALL partials (<=1024,
// L2-hot) in LDS to get its own offset, then scans its chunk and writes the
// cursor array. Block 0 also writes segment totals out1[n1]/out2[n2].
// ---------------------------------------------------------------------------
__global__ __launch_bounds__(256) void scan_apply_kernel(
    const int* __restrict__ a1, int* __restrict__ out1, int n1,
    const int* __restrict__ a2, int* __restrict__ out2, int n2,
    int B1, int nbtot, const int* __restrict__ partial)
{
    __shared__ int sExcl[1024];
    __shared__ int ws[4];
    const int tid = threadIdx.x;
    const int lane = tid & 63, wid = tid >> 6;

    int j0 = 4 * tid;
    int p0 = (j0 + 0 < nbtot) ? partial[j0 + 0] : 0;
    int p1 = (j0 + 1 < nbtot) ? partial[j0 + 1] : 0;
    int p2 = (j0 + 2 < nbtot) ? partial[j0 + 2] : 0;
    int p3 = (j0 + 3 < nbtot) ? partial[j0 + 3] : 0;
    int psum = p0 + p1 + p2 + p3;
    int P = psum;
    #pragma unroll
    for (int off = 1; off < 64; off <<= 1) {
        int u = __shfl_up(P, off, 64);
        if (lane >= off) P += u;
    }
    if (lane == 63) ws[wid] = P;
    __syncthreads();
    int wbase = 0;
    #pragma unroll
    for (int w = 0; w < 4; ++w) wbase += (w < wid) ? ws[w] : 0;
    int e = wbase + (P - psum);
    sExcl[j0 + 0] = e;
    sExcl[j0 + 1] = e + p0;
    sExcl[j0 + 2] = e + p0 + p1;
    sExcl[j0 + 3] = e + p0 + p1 + p2;
    __syncthreads();

    const int b = blockIdx.x;
    int tot1 = sExcl[B1 - 1] + partial[B1 - 1];
    int myOff = sExcl[b] - ((b >= B1) ? tot1 : 0);
    if (b == 0 && tid == 0) {
        int tot2 = sExcl[nbtot - 1] + partial[nbtot - 1] - tot1;
        out1[n1] = tot1;
        out2[n2] = tot2;
    }
    __syncthreads();

    const int* a; int* out; int n, base;
    if (b < B1) { a = a1; out = out1; n = n1; base = b * SCAN_CHUNK; }
    else        { a = a2; out = out2; n = n2; base = (b - B1) * SCAN_CHUNK; }
    int i0 = base + 2 * tid, i1 = i0 + 1;
    int x0 = (i0 < n) ? a[i0] : 0;
    int x1 = (i1 < n) ? a[i1] : 0;
    int p = x0 + x1;
    int Q = p;
    #pragma unroll
    for (int off = 1; off < 64; off <<= 1) {
        int u = __shfl_up(Q, off, 64);
        if (lane >= off) Q += u;
    }
    if (lane == 63) ws[wid] = Q;
    __syncthreads();
    int waveBase = 0;
    #pragma unroll
    for (int w = 0; w < 4; ++w) waveBase += (w < wid) ? ws[w] : 0;
    int off0 = myOff + waveBase + (Q - p);
    if (i0 < n) out[i0] = off0;
    if (i1 < n) out[i1] = off0 + x0;
}

// ---------------------------------------------------------------------------
// Partition pass 2: write packed (localkey<<17|other) u32s to per-(bucket,
// block) runs. LDS-atomic cursors only; runs contiguous & L2-resident.
// ---------------------------------------------------------------------------
__global__ __launch_bounds__(256) void part_scatter_kernel(
    const int* __restrict__ es, const int* __restrict__ ed,
    const int* __restrict__ baseD, const int* __restrict__ baseG,
    u32* __restrict__ pairD, u32* __restrict__ pairG,
    int ne, int shiftD, int shiftG)
{
    __shared__ int curD[256], curG[256];
    const int tid = threadIdx.x;
    curD[tid] = baseD[tid * NB1 + blockIdx.x];
    curG[tid] = baseG[tid * NB1 + blockIdx.x];
    __syncthreads();
    const int maskD = (1 << shiftD) - 1;
    const int maskG = (1 << shiftG) - 1;
    const int chunk = (ne + NB1 - 1) / NB1;
    const int e0 = blockIdx.x * chunk;
    const int e1 = min(e0 + chunk, ne);
    for (int e = e0 + tid; e < e1; e += 256) {
        int s = es[e], d = ed[e];
        int pD = atomicAdd(&curD[d >> shiftD], 1);
        pairD[pD] = ((u32)(d & maskD) << 17) | (u32)s;
        int pG = atomicAdd(&curG[s >> shiftG], 1);
        pairG[pG] = ((u32)(s & maskG) << 17) | (u32)d;
    }
}

// ---------------------------------------------------------------------------
// CSR finalize: one block per bucket. LDS hist -> LDS scan -> row[]; second
// sweep ranks with LDS atomics, writes idx[]. No global atomics.
// ---------------------------------------------------------------------------
__global__ __launch_bounds__(256) void csr_build_kernel(
    const u32* __restrict__ pairD, const int* __restrict__ baseD,
    int* __restrict__ rowD, int* __restrict__ idxD, int nd, int shiftD, int nbktD,
    const u32* __restrict__ pairG, const int* __restrict__ baseG,
    int* __restrict__ rowG, int* __restrict__ idxG, int ng, int shiftG, int nbktG)
{
    __shared__ int lcnt[512], lcur[512];
    __shared__ int ws[4];
    const int j = blockIdx.x & 255;
    const int isG = blockIdx.x >> 8;
    const u32* pair; const int* base; int* row; int* idx; int n, shift, nbkt;
    if (isG) { pair = pairG; base = baseG; row = rowG; idx = idxG; n = ng; shift = shiftG; nbkt = nbktG; }
    else     { pair = pairD; base = baseD; row = rowD; idx = idxD; n = nd; shift = shiftD; nbkt = nbktD; }
    if (j >= nbkt) return;

    const int tid = threadIdx.x;
    const int nLo = j << shift;
    const int nHi = min(nLo + (1 << shift), n);
    const int range = nHi - nLo;               // <= 512
    const int segBase = base[j * NB1];
    const int segEnd  = base[(j + 1) * NB1];

    lcnt[tid] = 0; lcnt[tid + 256] = 0;
    __syncthreads();
    for (int t = segBase + tid; t < segEnd; t += 256)
        atomicAdd(&lcnt[pair[t] >> 17], 1);
    __syncthreads();

    int i0 = 2 * tid, i1 = i0 + 1;
    int c0 = (i0 < range) ? lcnt[i0] : 0;
    int c1 = (i1 < range) ? lcnt[i1] : 0;
    int p = c0 + c1;
    int P = p;
    const int lane = tid & 63, wid = tid >> 6;
    #pragma unroll
    for (int off = 1; off < 64; off <<= 1) {
        int u = __shfl_up(P, off, 64);
        if (lane >= off) P += u;
    }
    if (lane == 63) ws[wid] = P;
    __syncthreads();
    int waveBase = 0;
    #pragma unroll
    for (int w = 0; w < 4; ++w) waveBase += (w < wid) ? ws[w] : 0;
    int o0 = segBase + waveBase + (P - p);
    int o1 = o0 + c0;
    if (i0 < range) { row[nLo + i0] = o0; lcur[i0] = o0; }
    if (i1 < range) { row[nLo + i1] = o1; lcur[i1] = o1; }
    if (nHi == n && tid == 0) row[n] = segEnd;
    __syncthreads();

    for (int t = segBase + tid; t < segEnd; t += 256) {
        u32 pr = pair[t];
        int pos = atomicAdd(&lcur[pr >> 17], 1);
        idx[pos] = (int)(pr & 0x1FFFFu);
    }
}

// ---------------------------------------------------------------------------
// Gather-mean over fp8(x16) 64 B rows -> bf16 means. HALF-WAVE (32 lanes)
// per node (standalone, 8-edge loop, low VGPR -> ~77% occupancy; waves
// retire independently). ALL sources fp8; descale 1/16 folded into inv.
// ---------------------------------------------------------------------------
__global__ __launch_bounds__(256) void gather_mean_kernel(
    const u8* __restrict__ srcD, const u8* __restrict__ srcG,
    const int* __restrict__ rowD, const int* __restrict__ idxD,
    const int* __restrict__ rowG, const int* __restrict__ idxG,
    u16* __restrict__ outD, u16* __restrict__ outG, int nd, int ng)
{
    int hw = blockIdx.x * 8 + (threadIdx.x >> 5);   // half-wave id = node
    int l5 = threadIdx.x & 31;
    if (hw >= nd + ng) return;
    const bool isD = hw < nd;
    const int sub = l5 >> 3;        // 0..3: edge slot
    const int c8 = l5 & 7;          // uint2 index within 64 B row
    const u8* src; const int* row; const int* idx; u16* out; int node;
    if (isD) { src = srcD; row = rowD; idx = idxD; out = outD; node = hw; }
    else     { src = srcG; row = rowG; idx = idxG; out = outG; node = hw - nd; }
    int beg = row[node], end = row[node + 1];

    float a0[8], a1[8];
    #pragma unroll
    for (int j = 0; j < 8; ++j) { a0[j] = 0.f; a1[j] = 0.f; }

    int i = beg;
    for (; i + 8 <= end; i += 8) {
        int s0 = idx[i + sub];
        int s1 = idx[i + 4 + sub];
        uint2 v0 = *((const uint2*)(src + (size_t)s0 * 64) + c8);
        uint2 v1 = *((const uint2*)(src + (size_t)s1 * 64) + c8);
        f32x2 f;
        f = __builtin_amdgcn_cvt_pk_f32_fp8((int)v0.x, false); a0[0] += f.x; a0[1] += f.y;
        f = __builtin_amdgcn_cvt_pk_f32_fp8((int)v0.x, true);  a0[2] += f.x; a0[3] += f.y;
        f = __builtin_amdgcn_cvt_pk_f32_fp8((int)v0.y, false); a0[4] += f.x; a0[5] += f.y;
        f = __builtin_amdgcn_cvt_pk_f32_fp8((int)v0.y, true);  a0[6] += f.x; a0[7] += f.y;
        f = __builtin_amdgcn_cvt_pk_f32_fp8((int)v1.x, false); a1[0] += f.x; a1[1] += f.y;
        f = __builtin_amdgcn_cvt_pk_f32_fp8((int)v1.x, true);  a1[2] += f.x; a1[3] += f.y;
        f = __builtin_amdgcn_cvt_pk_f32_fp8((int)v1.y, false); a1[4] += f.x; a1[5] += f.y;
        f = __builtin_amdgcn_cvt_pk_f32_fp8((int)v1.y, true);  a1[6] += f.x; a1[7] += f.y;
    }
    if (i + 4 <= end) {
        int s0 = idx[i + sub];
        uint2 v0 = *((const uint2*)(src + (size_t)s0 * 64) + c8);
        f32x2 f;
        f = __builtin_amdgcn_cvt_pk_f32_fp8((int)v0.x, false); a0[0] += f.x; a0[1] += f.y;
        f = __builtin_amdgcn_cvt_pk_f32_fp8((int)v0.x, true);  a0[2] += f.x; a0[3] += f.y;
        f = __builtin_amdgcn_cvt_pk_f32_fp8((int)v0.y, false); a0[4] += f.x; a0[5] += f.y;
        f = __builtin_amdgcn_cvt_pk_f32_fp8((int)v0.y, true);  a0[6] += f.x; a0[7] += f.y;
        i += 4;
    }
    if (i + sub < end) {
        int s1 = idx[i + sub];
        uint2 v1 = *((const uint2*)(src + (size_t)s1 * 64) + c8);
        f32x2 f;
        f = __builtin_amdgcn_cvt_pk_f32_fp8((int)v1.x, false); a1[0] += f.x; a1[1] += f.y;
        f = __builtin_amdgcn_cvt_pk_f32_fp8((int)v1.x, true);  a1[2] += f.x; a1[3] += f.y;
        f = __builtin_amdgcn_cvt_pk_f32_fp8((int)v1.y, false); a1[4] += f.x; a1[5] += f.y;
        f = __builtin_amdgcn_cvt_pk_f32_fp8((int)v1.y, true);  a1[6] += f.x; a1[7] += f.y;
    }

    float acc[8];
    #pragma unroll
    for (int j = 0; j < 8; ++j) acc[j] = a0[j] + a1[j];
    #pragma unroll
    for (int j = 0; j < 8; ++j) {
        acc[j] += __shfl_xor(acc[j], 8, 64);
        acc[j] += __shfl_xor(acc[j], 16, 64);
    }
    if (sub == 0) {
        float inv = 0.0625f / fmaxf((float)(end - beg), 1.0f);  // 1/16 descale
        u32 w0 = (u32)bf16rne(acc[0] * inv) | ((u32)bf16rne(acc[1] * inv) << 16);
        u32 w1 = (u32)bf16rne(acc[2] * inv) | ((u32)bf16rne(acc[3] * inv) << 16);
        u32 w2 = (u32)bf16rne(acc[4] * inv) | ((u32)bf16rne(acc[5] * inv) << 16);
        u32 w3 = (u32)bf16rne(acc[6] * inv) | ((u32)bf16rne(acc[7] * inv) << 16);
        uint4 pk = make_uint4(w0, w1, w2, w3);
        *(uint4*)(out + (size_t)node * H + c8 * 8) = pk;
    }
}

// ---------------------------------------------------------------------------
// SAGE linear via MFMA, BOTH directions in one dispatch.
// F8OUT: additionally emit the output rows as fp8(x16) 64 B rows (for the
// next layer's gather sources). Error: fp8 only feeds the mean path; the
// x-operand path stays bf16.
// ---------------------------------------------------------------------------
template <bool RELU, bool F8OUT>
__global__ __launch_bounds__(256) void sage_mm_mfma_kernel(
    const u16* __restrict__ meanD, const u16* __restrict__ xD, u16* __restrict__ outD,
    u8* __restrict__ outDf8,
    const float* __restrict__ wlD, const float* __restrict__ wrD,
    const float* __restrict__ bD, int nd,
    const u16* __restrict__ meanG, const u16* __restrict__ xG, u16* __restrict__ outG,
    u8* __restrict__ outGf8,
    const float* __restrict__ wlG, const float* __restrict__ wrG,
    const float* __restrict__ bG, int ng, int MBD)
{
    __shared__ u16 sB[16 * 64 * 8];   // [frag=c*4+t][lane][j]
    int b = blockIdx.x;
    const u16 *mean, *x; u16* out; u8* out8; const float *wl, *wr, *bias; int n;
    if (b < MBD) { mean = meanD; x = xD; out = outD; out8 = outDf8; wl = wlD; wr = wrD; bias = bD; n = nd; }
    else { b -= MBD; mean = meanG; x = xG; out = outG; out8 = outGf8; wl = wlG; wr = wrG; bias = bG; n = ng; }

    const int tid = threadIdx.x;
    for (int i = tid; i < 4096; i += 256) {
        int k = i >> 6, ncol = i & 63;
        int q = (k >> 3) & 3, j = k & 7, t = ncol >> 4, n15 = ncol & 15;
        int lane = q * 16 + n15;
        int c0 = k >> 5;                     // 0..1
        sB[(((c0 + 0) * 4 + t) * 64 + lane) * 8 + j] = bf16rne(wl[i]);
        sB[(((c0 + 2) * 4 + t) * 64 + lane) * 8 + j] = bf16rne(wr[i]);
    }
    __syncthreads();

    const int lane = tid & 63;
    const int wave = tid >> 6;
    const int m = lane & 15;
    const int q = lane >> 4;

    bf16x8 Bf[16];
    {
        const uint4* sB4 = (const uint4*)sB;
        #pragma unroll
        for (int f = 0; f < 16; ++f)
            Bf[f] = __builtin_bit_cast(bf16x8, sB4[f * 64 + lane]);
    }
    float bv[4];
    #pragma unroll
    for (int t = 0; t < 4; ++t) bv[t] = bias[t * 16 + m];

    const int row0 = b * 256;
    #pragma unroll
    for (int r = 0; r < 4; ++r) {
        int rbase = row0 + (wave + 4 * r) * 16;   // wave-uniform
        if (rbase >= n) break;
        int gr = min(rbase + m, n - 1);
        const uint4* mrow = (const uint4*)(mean + (size_t)gr * H);
        const uint4* xrow = (const uint4*)(x + (size_t)gr * H);
        bf16x8 A0 = __builtin_bit_cast(bf16x8, mrow[q]);
        bf16x8 A1 = __builtin_bit_cast(bf16x8, mrow[q + 4]);
        bf16x8 A2 = __builtin_bit_cast(bf16x8, xrow[q]);
        bf16x8 A3 = __builtin_bit_cast(bf16x8, xrow[q + 4]);
        f32x4 acc[4];
        #pragma unroll
        for (int t = 0; t < 4; ++t) acc[t] = (f32x4){bv[t], bv[t], bv[t], bv[t]};
        #pragma unroll
        for (int t = 0; t < 4; ++t) {
            acc[t] = __builtin_amdgcn_mfma_f32_16x16x32_bf16(A0, Bf[0 * 4 + t], acc[t], 0, 0, 0);
            acc[t] = __builtin_amdgcn_mfma_f32_16x16x32_bf16(A1, Bf[1 * 4 + t], acc[t], 0, 0, 0);
            acc[t] = __builtin_amdgcn_mfma_f32_16x16x32_bf16(A2, Bf[2 * 4 + t], acc[t], 0, 0, 0);
            acc[t] = __builtin_amdgcn_mfma_f32_16x16x32_bf16(A3, Bf[3 * 4 + t], acc[t], 0, 0, 0);
        }
        #pragma unroll
        for (int reg = 0; reg < 4; ++reg) {
            int orow = rbase + q * 4 + reg;
            if (orow < n) {
                u16* op = out + (size_t)orow * H;
                u8* op8 = F8OUT ? (out8 + (size_t)orow * H) : nullptr;
                #pragma unroll
                for (int t = 0; t < 4; ++t) {
                    float v = acc[t][reg];
                    if (RELU) v = fmaxf(v, 0.0f);
                    op[t * 16 + m] = bf16rne(v);
                    if (F8OUT) op8[t * 16 + m] = fp8enc(v * 16.0f);
                }
            }
        }
    }
}

// ---------------------------------------------------------------------------
// Classifier on bf16 rows: 8 lanes per edge, uint4 loads, fp32 dot,
// 3-stage xor reduce within the 8-lane group. (Label-sort removed: R11
// measured it as a net -24 us regression.)
// ---------------------------------------------------------------------------
__global__ __launch_bounds__(256) void classify_kernel(
    const u16* __restrict__ hg2, const u16* __restrict__ hd2,
    const int* __restrict__ ls, const int* __restrict__ ld,
    float* __restrict__ out, int nl)
{
    long long t = (long long)blockIdx.x * blockDim.x + threadIdx.x;
    int e = (int)(t >> 3);
    int c8 = (int)(t & 7);
    if (e >= nl) return;
    int a = ls[e];
    int b = ld[e];
    uint4 ua = *((const uint4*)(hg2 + (size_t)a * H) + c8);
    uint4 ub = *((const uint4*)(hd2 + (size_t)b * H) + c8);
    float v = bflo(ua.x) * bflo(ub.x) + bfhi(ua.x) * bfhi(ub.x)
            + bflo(ua.y) * bflo(ub.y) + bfhi(ua.y) * bfhi(ub.y)
            + bflo(ua.z) * bflo(ub.z) + bfhi(ua.z) * bfhi(ub.z)
            + bflo(ua.w) * bflo(ub.w) + bfhi(ua.w) * bfhi(ub.w);
    v += __shfl_xor(v, 1, 64);
    v += __shfl_xor(v, 2, 64);
    v += __shfl_xor(v, 4, 64);
    if (c8 == 0) out[e] = v;
}

extern "C" void kernel_launch(void* const* d_in, const int* in_sizes, int n_in,
                              void* d_out, int out_size, void* d_ws, size_t ws_size,
                              hipStream_t stream)
{
    const float* gene  = (const float*)d_in[0];
    const float* dis   = (const float*)d_in[1];
    const float* w1gdl = (const float*)d_in[2];
    const float* w1gdr = (const float*)d_in[3];
    const float* w1dgl = (const float*)d_in[4];
    const float* w1dgr = (const float*)d_in[5];
    const float* w2gdl = (const float*)d_in[6];
    const float* w2gdr = (const float*)d_in[7];
    const float* w2dgl = (const float*)d_in[8];
    const float* w2dgr = (const float*)d_in[9];
    const float* b1gd  = (const float*)d_in[10];
    const float* b1dg  = (const float*)d_in[11];
    const float* b2gd  = (const float*)d_in[12];
    const float* b2dg  = (const float*)d_in[13];
    const int* es = (const int*)d_in[14];
    const int* ed = (const int*)d_in[15];
    const int* ls = (const int*)d_in[16];
    const int* ld = (const int*)d_in[17];

    const int ng = in_sizes[0] / H;   // 100000
    const int nd = in_sizes[1] / H;   // 30000
    const int ne = in_sizes[14];      // 1500000
    const int nl = in_sizes[16];      // 500000

    int shiftD = 0; while (((nd + (1 << shiftD) - 1) >> shiftD) > 256) ++shiftD;  // 7
    int shiftG = 0; while (((ng + (1 << shiftG) - 1) >> shiftG) > 256) ++shiftG;  // 9
    const int nbktD = (nd + (1 << shiftD) - 1) >> shiftD;
    const int nbktG = (ng + (1 << shiftG) - 1) >> shiftG;
    const int n1 = 256 * NB1;

    // --- Workspace layout ---
    int* rowD = (int*)d_ws;                         // nd+1
    int* rowG = rowD + nd + 1;                      // ng+1
    int* idxD = rowG + ng + 1;                      // ne
    int* idxG = idxD + ne;                          // ne
    u16* geneBf = (u16*)(idxG + ne);                // ng*H
    u16* disBf  = geneBf + (size_t)ng * H;          // nd*H
    u16* h1Dbf  = disBf + (size_t)nd * H;           // nd*H
    u16* h1Gbf  = h1Dbf + (size_t)nd * H;           // ng*H
    u16* h2Dbf  = h1Gbf + (size_t)ng * H;           // nd*H
    u16* h2Gbf  = h2Dbf + (size_t)nd * H;           // ng*H
    uintptr_t pf8 = (uintptr_t)(h2Gbf + (size_t)ng * H);
    pf8 = (pf8 + 15) & ~(uintptr_t)15;
    u32* geneF8 = (u32*)pf8;                        // ng*16 (fp8 x16 rows)
    u32* disF8  = geneF8 + (size_t)ng * 16;         // nd*16
    u32* h1DF8  = disF8 + (size_t)nd * 16;          // nd*16
    u32* h1GF8  = h1DF8 + (size_t)nd * 16;          // ng*16
    uintptr_t p = (uintptr_t)(h1GF8 + (size_t)ng * 16);
    p = (p + 15) & ~(uintptr_t)15;
    // Union region: CSR-build scratch (dead after csr_build) aliased w/ means.
    u16* MD = (u16*)p;                              // nd*H bf16 means
    u16* MG = MD + (size_t)nd * H;                  // ng*H
    int* histD = (int*)p;                           // n1
    int* histG = histD + n1;                        // n1
    int* baseD = histG + n1;                        // n1+1
    int* baseG = baseD + n1 + 1;                    // n1+1
    int* partial  = baseG + n1 + 1;                 // 1024
    uintptr_t pp = (uintptr_t)(partial + 1024);
    pp = (pp + 15) & ~(uintptr_t)15;
    u32* pairD = (u32*)pp;                          // ne
    u32* pairG = pairD + ne;                        // ne

    // --- Dispatch 1: edge histogram || table conversion (bf16 + fp8) ---
    const long long na4 = (long long)ng * H / 4;
    const long long nb4 = (long long)nd * H / 4;
    const int convBlocks = (int)((na4 + nb4 + 255) / 256);
    fused_count_convert_kernel<<<NB1 + convBlocks, 256, 0, stream>>>(
        es, ed, histD, histG, ne, shiftD, shiftG,
        gene, geneBf, geneF8, na4, dis, disBf, disF8, nb4);

    // --- Dispatch 2-3: scans (2 segments) ---
    const int B1 = n1 / SCAN_CHUNK;          // 256
    const int nbtot = 2 * B1;                // 512
    scan_reduce_kernel<<<nbtot, 256, 0, stream>>>(histD, n1, histG, n1, B1, partial);
    scan_apply_kernel<<<nbtot, 256, 0, stream>>>(histD, baseD, n1,
                                                 histG, baseG, n1, B1, nbtot, partial);

    // --- Dispatch 4: edge pair partition ---
    part_scatter_kernel<<<NB1, 256, 0, stream>>>(es, ed, baseD, baseG,
                                                 pairD, pairG, ne, shiftD, shiftG);
    // --- Dispatch 5: CSR finalize ---
    csr_build_kernel<<<512, 256, 0, stream>>>(
        pairD, baseD, rowD, idxD, nd, shiftD, nbktD,
        pairG, baseG, rowG, idxG, ng, shiftG, nbktG);

    const int gatherBlocks = (nd + ng + 7) / 8;
    const int MBD = (nd + 255) / 256;
    const int MBG = (ng + 255) / 256;

    // --- Layer 1: all-fp8 gather sources; mm emits bf16 + fp8 h1 ---
    gather_mean_kernel<<<gatherBlocks, 256, 0, stream>>>(
        (const u8*)geneF8, (const u8*)disF8, rowD, idxD, rowG, idxG, MD, MG, nd, ng);
    sage_mm_mfma_kernel<true, true><<<MBD + MBG, 256, 0, stream>>>(
        MD, disBf, h1Dbf, (u8*)h1DF8, w1gdl, w1gdr, b1gd, nd,
        MG, geneBf, h1Gbf, (u8*)h1GF8, w1dgl, w1dgr, b1dg, ng, MBD);

    // --- Layer 2: fp8 h1 gather sources; mm emits bf16 h2 only ---
    gather_mean_kernel<<<gatherBlocks, 256, 0, stream>>>(
        (const u8*)h1GF8, (const u8*)h1DF8, rowD, idxD, rowG, idxG, MD, MG, nd, ng);
    sage_mm_mfma_kernel<false, false><<<MBD + MBG, 256, 0, stream>>>(
        MD, h1Dbf, h2Dbf, nullptr, w2gdl, w2gdr, b2gd, nd,
        MG, h1Gbf, h2Gbf, nullptr, w2dgl, w2dgr, b2dg, ng, MBD);

    // --- Classifier ---
    {
        long long threads = (long long)nl * 8;
        int blocks = (int)((threads + 255) / 256);
        classify_kernel<<<blocks, 256, 0, stream>>>(h2Gbf, h2Dbf, ls, ld,
                                                    (float*)d_out, nl);
    }
}